// Round 1
// baseline (28.266 us; speedup 1.0000x reference)
//
#include <hip/hip_runtime.h>
#include <math.h>

// Problem constants (B=2, N_RES=512, N_ATOMS=4)
#define NPTS    2048                  // points per batch = N_RES*N_ATOMS
#define BATCH   2
#define TOTAL_I (BATCH * NPTS)        // 4096
#define JCHUNKS 16
#define JLEN    (NPTS / JCHUNKS)      // 128 j-iterations per thread
#define THREADS 256
#define NBLOCKS (TOTAL_I * JCHUNKS / THREADS)  // 256 blocks -> ~1 per CU

__global__ __launch_bounds__(THREADS) void pair_loss_kernel(
    const float* __restrict__ pred, const float* __restrict__ nat,
    const int* __restrict__ mask, float* __restrict__ ws_sum, float inv_d0)
{
    const int bid    = blockIdx.x;
    const int chunk  = bid / (TOTAL_I / THREADS);            // 0..15, block-uniform
    const int igBase = (bid % (TOTAL_I / THREADS)) * THREADS; // block-uniform
    const int b      = igBase / NPTS;                         // block-uniform batch
    const int i      = igBase - b * NPTS + threadIdx.x;       // per-lane i in [0,NPTS)

    const float* __restrict__ pb = pred + (size_t)b * NPTS * 3;
    const float* __restrict__ nb = nat  + (size_t)b * NPTS * 3;
    const int*   __restrict__ mb = mask + b * NPTS;

    // per-lane i-point coords in registers
    const float pix = pb[i * 3 + 0], piy = pb[i * 3 + 1], piz = pb[i * 3 + 2];
    const float nix = nb[i * 3 + 0], niy = nb[i * 3 + 1], niz = nb[i * 3 + 2];
    const float mi  = (float)mb[i];

    float acc = 0.0f;
    const int j0 = chunk * JLEN;
    #pragma unroll 4
    for (int jj = 0; jj < JLEN; ++jj) {
        const int j = j0 + jj;                 // wave-uniform address stream
        const float dx = pix - pb[j * 3 + 0];
        const float dy = piy - pb[j * 3 + 1];
        const float dz = piz - pb[j * 3 + 2];
        const float pd = __builtin_amdgcn_sqrtf(dx * dx + dy * dy + dz * dz);
        const float ex = nix - nb[j * 3 + 0];
        const float ey = niy - nb[j * 3 + 1];
        const float ez = niz - nb[j * 3 + 2];
        const float nd = __builtin_amdgcn_sqrtf(ex * ex + ey * ey + ez * ez);
        const float t    = (pd - nd) * inv_d0;
        const float prox = __builtin_amdgcn_rcpf(1.0f + t * t);
        acc += prox * (float)mb[j];            // only mask_j pairs count
    }
    acc *= mi;                                 // gate by mask_i

    // wave (64-lane) shuffle reduction
    for (int off = 32; off > 0; off >>= 1)
        acc += __shfl_down(acc, off, 64);

    __shared__ float wsum[THREADS / 64];
    const int lane = threadIdx.x & 63;
    const int wid  = threadIdx.x >> 6;
    if (lane == 0) wsum[wid] = acc;
    __syncthreads();
    if (threadIdx.x == 0) {
        float s = 0.0f;
        #pragma unroll
        for (int w = 0; w < THREADS / 64; ++w) s += wsum[w];
        atomicAdd(ws_sum, s);
    }
}

__global__ __launch_bounds__(256) void finalize_kernel(
    const int* __restrict__ mask, const float* __restrict__ ws_sum,
    float* __restrict__ out)
{
    __shared__ int cnt0, cnt1;
    if (threadIdx.x == 0) { cnt0 = 0; cnt1 = 0; }
    __syncthreads();

    int l0 = 0, l1 = 0;
    for (int k = threadIdx.x; k < NPTS; k += blockDim.x) {
        l0 += (mask[k] != 0);
        l1 += (mask[NPTS + k] != 0);
    }
    // wave-level reduce then shared atomics (tiny kernel, contention irrelevant)
    for (int off = 32; off > 0; off >>= 1) {
        l0 += __shfl_down(l0, off, 64);
        l1 += __shfl_down(l1, off, 64);
    }
    if ((threadIdx.x & 63) == 0) {
        atomicAdd(&cnt0, l0);
        atomicAdd(&cnt1, l1);
    }
    __syncthreads();
    if (threadIdx.x == 0) {
        const double c0 = (double)cnt0, c1 = (double)cnt1;
        const double count = c0 * c0 + c1 * c1;
        out[0] = (float)(-(double)ws_sum[0] / count);
    }
}

extern "C" void kernel_launch(void* const* d_in, const int* in_sizes, int n_in,
                              void* d_out, int out_size, void* d_ws, size_t ws_size,
                              hipStream_t stream) {
    const float* pred = (const float*)d_in[0];
    const float* nat  = (const float*)d_in[1];
    const int*   mask = (const int*)d_in[2];
    float* out = (float*)d_out;
    float* ws  = (float*)d_ws;

    // zero the global accumulator each call (harness does not re-poison between replays)
    hipMemsetAsync(ws, 0, sizeof(float), stream);

    // d0 = 1.24 * (n_res - 15)^(1/3) - 1.8, n_res = 512 (host-side pure math)
    const double d0 = 1.24 * cbrt(512.0 - 15.0) - 1.8;
    const float inv_d0 = (float)(1.0 / d0);

    pair_loss_kernel<<<NBLOCKS, THREADS, 0, stream>>>(pred, nat, mask, ws, inv_d0);
    finalize_kernel<<<1, 256, 0, stream>>>(mask, ws, out);
}